// Round 1
// baseline (580.356 us; speedup 1.0000x reference)
//
#include <hip/hip_runtime.h>
#include <stdint.h>

#define NB 16
#define NPIX 262144            // 512*512
#define K_RANK 104856u         // int(512*512*0.4 - 1)
#define NB1 4096

// ---------------- Kernel 1: gray + histogram on bits[31:20] ----------------
__global__ void k_gray_hist(const float* __restrict__ yp, float* __restrict__ gray,
                            unsigned* __restrict__ hist1) {
    __shared__ unsigned h[NB1];
    const int tid = threadIdx.x;
    for (int i = tid; i < NB1; i += 256) h[i] = 0;
    __syncthreads();

    const int blk   = blockIdx.x;      // 4096 blocks, 256 per batch
    const int b     = blk >> 8;
    const int chunk = blk & 255;
    const long base = (long)b * 3 * NPIX;
    const int  o    = (chunk * 256 + tid) * 4;

    const float4 c0 = *(const float4*)(yp + base + o);
    const float4 c1 = *(const float4*)(yp + base + NPIX + o);
    const float4 c2 = *(const float4*)(yp + base + 2 * NPIX + o);

    float g0 = (c0.x + c1.x + c2.x) / 3.0f;
    float g1 = (c0.y + c1.y + c2.y) / 3.0f;
    float g2 = (c0.z + c1.z + c2.z) / 3.0f;
    float g3 = (c0.w + c1.w + c2.w) / 3.0f;

    if (gray) {
        *(float4*)(gray + (long)b * NPIX + o) = make_float4(g0, g1, g2, g3);
    }
    atomicAdd(&h[__float_as_uint(g0) >> 20], 1u);
    atomicAdd(&h[__float_as_uint(g1) >> 20], 1u);
    atomicAdd(&h[__float_as_uint(g2) >> 20], 1u);
    atomicAdd(&h[__float_as_uint(g3) >> 20], 1u);
    __syncthreads();

    unsigned* gh = hist1 + b * NB1;
    for (int i = tid; i < NB1; i += 256) {
        unsigned v = h[i];
        if (v) atomicAdd(&gh[i], v);
    }
}

// ---------------- Scan: pick digit containing the rank ----------------
__global__ void k_scan(const unsigned* __restrict__ hist, int nbins, int width,
                       unsigned* __restrict__ rank, unsigned* __restrict__ prefix,
                       int first) {
    const int b = threadIdx.x;
    if (b >= NB) return;
    unsigned r = first ? K_RANK : rank[b];
    unsigned p = first ? 0u : prefix[b];
    const unsigned* hb = hist + b * nbins;
    unsigned cum = 0, d = 0;
    for (int j = 0; j < nbins; ++j) {
        unsigned c = hb[j];
        if (cum + c > r) { d = (unsigned)j; break; }
        cum += c;
    }
    rank[b]   = r - cum;
    prefix[b] = (p << width) | d;
}

// ---------------- Refine: histogram next digit among prefix-matching ----------------
__global__ void k_refine(const float* __restrict__ gray, const float* __restrict__ yp,
                         const unsigned* __restrict__ prefix, unsigned* __restrict__ hist,
                         int sel_shift, int dig_shift, unsigned dmask, int nbins) {
    __shared__ unsigned h[NB1];
    const int tid = threadIdx.x;
    for (int i = tid; i < nbins; i += 256) h[i] = 0;
    __syncthreads();

    const int blk   = blockIdx.x;
    const int b     = blk >> 8;
    const int chunk = blk & 255;
    const int o     = (chunk * 256 + tid) * 4;

    float g0, g1, g2, g3;
    if (gray) {
        float4 gv = *(const float4*)(gray + (long)b * NPIX + o);
        g0 = gv.x; g1 = gv.y; g2 = gv.z; g3 = gv.w;
    } else {
        const long base = (long)b * 3 * NPIX;
        float4 c0 = *(const float4*)(yp + base + o);
        float4 c1 = *(const float4*)(yp + base + NPIX + o);
        float4 c2 = *(const float4*)(yp + base + 2 * NPIX + o);
        g0 = (c0.x + c1.x + c2.x) / 3.0f;
        g1 = (c0.y + c1.y + c2.y) / 3.0f;
        g2 = (c0.z + c1.z + c2.z) / 3.0f;
        g3 = (c0.w + c1.w + c2.w) / 3.0f;
    }
    const unsigned pre = prefix[b];
    unsigned bits;
    bits = __float_as_uint(g0);
    if ((bits >> sel_shift) == pre) atomicAdd(&h[(bits >> dig_shift) & dmask], 1u);
    bits = __float_as_uint(g1);
    if ((bits >> sel_shift) == pre) atomicAdd(&h[(bits >> dig_shift) & dmask], 1u);
    bits = __float_as_uint(g2);
    if ((bits >> sel_shift) == pre) atomicAdd(&h[(bits >> dig_shift) & dmask], 1u);
    bits = __float_as_uint(g3);
    if ((bits >> sel_shift) == pre) atomicAdd(&h[(bits >> dig_shift) & dmask], 1u);
    __syncthreads();

    unsigned* gh = hist + b * nbins;
    for (int i = tid; i < nbins; i += 256) {
        unsigned v = h[i];
        if (v) atomicAdd(&gh[i], v);
    }
}

// ---------------- Loss: weighted L1, block-reduce, f64 atomic ----------------
__global__ void k_loss(const float* __restrict__ yt, const float* __restrict__ yp,
                       const unsigned* __restrict__ prefix, double* __restrict__ accum) {
    const int tid   = threadIdx.x;
    const int blk   = blockIdx.x;
    const int b     = blk >> 8;
    const int chunk = blk & 255;
    const long base = (long)b * 3 * NPIX;
    const int  o    = (chunk * 256 + tid) * 4;

    float4 p0 = *(const float4*)(yp + base + o);
    float4 p1 = *(const float4*)(yp + base + NPIX + o);
    float4 p2 = *(const float4*)(yp + base + 2 * NPIX + o);
    float4 t0 = *(const float4*)(yt + base + o);
    float4 t1 = *(const float4*)(yt + base + NPIX + o);
    float4 t2 = *(const float4*)(yt + base + 2 * NPIX + o);

    const unsigned thr = prefix[b];
    float s = 0.0f;
    {
        float g = (p0.x + p1.x + p2.x) / 3.0f;
        float w = (__float_as_uint(g) <= thr) ? 0.8f : 0.2f;
        s += w * (fabsf(p0.x - t0.x) + fabsf(p1.x - t1.x) + fabsf(p2.x - t2.x));
    }
    {
        float g = (p0.y + p1.y + p2.y) / 3.0f;
        float w = (__float_as_uint(g) <= thr) ? 0.8f : 0.2f;
        s += w * (fabsf(p0.y - t0.y) + fabsf(p1.y - t1.y) + fabsf(p2.y - t2.y));
    }
    {
        float g = (p0.z + p1.z + p2.z) / 3.0f;
        float w = (__float_as_uint(g) <= thr) ? 0.8f : 0.2f;
        s += w * (fabsf(p0.z - t0.z) + fabsf(p1.z - t1.z) + fabsf(p2.z - t2.z));
    }
    {
        float g = (p0.w + p1.w + p2.w) / 3.0f;
        float w = (__float_as_uint(g) <= thr) ? 0.8f : 0.2f;
        s += w * (fabsf(p0.w - t0.w) + fabsf(p1.w - t1.w) + fabsf(p2.w - t2.w));
    }

    // wave64 shuffle reduce
    for (int off = 32; off > 0; off >>= 1) s += __shfl_down(s, off);
    __shared__ float wsum[4];
    if ((tid & 63) == 0) wsum[tid >> 6] = s;
    __syncthreads();
    if (tid == 0) {
        float tot = wsum[0] + wsum[1] + wsum[2] + wsum[3];
        atomicAdd(accum, (double)tot);
    }
}

__global__ void k_final(const double* __restrict__ accum, float* __restrict__ out) {
    out[0] = (float)(accum[0] / 12582912.0);   // 16*3*512*512
}

extern "C" void kernel_launch(void* const* d_in, const int* in_sizes, int n_in,
                              void* d_out, int out_size, void* d_ws, size_t ws_size,
                              hipStream_t stream) {
    const float* yt = (const float*)d_in[0];   // y_true
    const float* yp = (const float*)d_in[1];   // y_pred
    float* out = (float*)d_out;
    char* ws = (char*)d_ws;

    // ws layout
    unsigned* hist1  = (unsigned*)(ws);              // 16*4096*4 = 262144
    unsigned* hist2  = (unsigned*)(ws + 262144);     // 262144
    unsigned* hist3  = (unsigned*)(ws + 524288);     // 16*256*4 = 16384
    double*   accum  = (double*)(ws + 540672);       // 8
    unsigned* rank   = (unsigned*)(ws + 540736);     // 64
    unsigned* prefix = (unsigned*)(ws + 540800);     // 64

    float* gray = nullptr;
    const size_t gray_off = 1 << 20;
    if (ws_size >= gray_off + (size_t)NB * NPIX * sizeof(float))
        gray = (float*)(ws + gray_off);

    // zero hist1..hist3 + accum (rank/prefix are written before read)
    hipMemsetAsync(ws, 0, 540680, stream);

    k_gray_hist<<<4096, 256, 0, stream>>>(yp, gray, hist1);
    k_scan<<<1, 64, 0, stream>>>(hist1, NB1, 12, rank, prefix, 1);
    k_refine<<<4096, 256, 0, stream>>>(gray, yp, prefix, hist2, 20, 8, 0xFFFu, NB1);
    k_scan<<<1, 64, 0, stream>>>(hist2, NB1, 12, rank, prefix, 0);
    k_refine<<<4096, 256, 0, stream>>>(gray, yp, prefix, hist3, 8, 0, 0xFFu, 256);
    k_scan<<<1, 64, 0, stream>>>(hist3, 256, 8, rank, prefix, 0);
    k_loss<<<4096, 256, 0, stream>>>(yt, yp, prefix, accum);
    k_final<<<1, 1, 0, stream>>>(accum, out);
}

// Round 2
// 195.971 us; speedup vs baseline: 2.9614x; 2.9614x over previous
//
#include <hip/hip_runtime.h>
#include <stdint.h>

#define NB 16
#define NPIX 262144            // 512*512
#define K_RANK 104856u         // int(512*512*0.4 - 1)
#define NB1 4096

// ---------------- Kernel 1: gray + histogram on bits[31:20] ----------------
__global__ void k_gray_hist(const float* __restrict__ yp, float* __restrict__ gray,
                            unsigned* __restrict__ hist1) {
    __shared__ unsigned h[NB1];
    const int tid = threadIdx.x;
    for (int i = tid; i < NB1; i += 256) h[i] = 0;
    __syncthreads();

    const int blk   = blockIdx.x;      // 4096 blocks, 256 per batch
    const int b     = blk >> 8;
    const int chunk = blk & 255;
    const long base = (long)b * 3 * NPIX;
    const int  o    = (chunk * 256 + tid) * 4;

    const float4 c0 = *(const float4*)(yp + base + o);
    const float4 c1 = *(const float4*)(yp + base + NPIX + o);
    const float4 c2 = *(const float4*)(yp + base + 2 * NPIX + o);

    float g0 = (c0.x + c1.x + c2.x) / 3.0f;
    float g1 = (c0.y + c1.y + c2.y) / 3.0f;
    float g2 = (c0.z + c1.z + c2.z) / 3.0f;
    float g3 = (c0.w + c1.w + c2.w) / 3.0f;

    if (gray) {
        *(float4*)(gray + (long)b * NPIX + o) = make_float4(g0, g1, g2, g3);
    }
    atomicAdd(&h[__float_as_uint(g0) >> 20], 1u);
    atomicAdd(&h[__float_as_uint(g1) >> 20], 1u);
    atomicAdd(&h[__float_as_uint(g2) >> 20], 1u);
    atomicAdd(&h[__float_as_uint(g3) >> 20], 1u);
    __syncthreads();

    unsigned* gh = hist1 + b * NB1;
    for (int i = tid; i < NB1; i += 256) {
        unsigned v = h[i];
        if (v) atomicAdd(&gh[i], v);
    }
}

// ---------------- Scan: pick digit containing the rank (parallel) ----------------
// grid = NB blocks, 256 threads each. Coalesced hist load -> LDS, per-thread
// partial sums, wave shuffle scan + cross-wave scan, bracket thread resolves digit.
__global__ void k_scan(const unsigned* __restrict__ hist, int nbins, int width,
                       unsigned* __restrict__ rank, unsigned* __restrict__ prefix,
                       int first) {
    __shared__ unsigned sh[NB1];
    __shared__ unsigned wave_sums[4];
    const int b   = blockIdx.x;
    const int tid = threadIdx.x;
    const unsigned* hb = hist + b * nbins;

    for (int i = tid; i < nbins; i += 256) sh[i] = hb[i];
    __syncthreads();

    const int per = nbins >> 8;             // 16 (4096 bins) or 1 (256 bins)
    unsigned sum = 0;
    for (int j = 0; j < per; ++j) sum += sh[tid * per + j];

    // inclusive scan within wave64
    unsigned inc = sum;
    for (int off = 1; off < 64; off <<= 1) {
        unsigned v = __shfl_up(inc, off);
        if ((tid & 63) >= off) inc += v;
    }
    if ((tid & 63) == 63) wave_sums[tid >> 6] = inc;
    __syncthreads();
    unsigned wave_off = 0;
    for (int w = 0; w < (tid >> 6); ++w) wave_off += wave_sums[w];
    const unsigned excl = wave_off + inc - sum;   // exclusive prefix of this thread

    const unsigned r = first ? K_RANK : rank[b];
    if (r >= excl && r < excl + sum) {            // exactly one thread
        unsigned cum = excl;
        unsigned d   = (unsigned)(tid * per);
        for (int j = 0; j < per; ++j) {
            unsigned c = sh[tid * per + j];
            if (cum + c > r) { d = (unsigned)(tid * per + j); break; }
            cum += c;
        }
        const unsigned p = first ? 0u : prefix[b];
        rank[b]   = r - cum;
        prefix[b] = (p << width) | d;
    }
}

// ---------------- Refine: histogram next digit among prefix-matching ----------------
__global__ void k_refine(const float* __restrict__ gray, const float* __restrict__ yp,
                         const unsigned* __restrict__ prefix, unsigned* __restrict__ hist,
                         int sel_shift, int dig_shift, unsigned dmask, int nbins) {
    __shared__ unsigned h[NB1];
    const int tid = threadIdx.x;
    for (int i = tid; i < nbins; i += 256) h[i] = 0;
    __syncthreads();

    const int blk   = blockIdx.x;
    const int b     = blk >> 8;
    const int chunk = blk & 255;
    const int o     = (chunk * 256 + tid) * 4;

    float g0, g1, g2, g3;
    if (gray) {
        float4 gv = *(const float4*)(gray + (long)b * NPIX + o);
        g0 = gv.x; g1 = gv.y; g2 = gv.z; g3 = gv.w;
    } else {
        const long base = (long)b * 3 * NPIX;
        float4 c0 = *(const float4*)(yp + base + o);
        float4 c1 = *(const float4*)(yp + base + NPIX + o);
        float4 c2 = *(const float4*)(yp + base + 2 * NPIX + o);
        g0 = (c0.x + c1.x + c2.x) / 3.0f;
        g1 = (c0.y + c1.y + c2.y) / 3.0f;
        g2 = (c0.z + c1.z + c2.z) / 3.0f;
        g3 = (c0.w + c1.w + c2.w) / 3.0f;
    }
    const unsigned pre = prefix[b];
    unsigned bits;
    bits = __float_as_uint(g0);
    if ((bits >> sel_shift) == pre) atomicAdd(&h[(bits >> dig_shift) & dmask], 1u);
    bits = __float_as_uint(g1);
    if ((bits >> sel_shift) == pre) atomicAdd(&h[(bits >> dig_shift) & dmask], 1u);
    bits = __float_as_uint(g2);
    if ((bits >> sel_shift) == pre) atomicAdd(&h[(bits >> dig_shift) & dmask], 1u);
    bits = __float_as_uint(g3);
    if ((bits >> sel_shift) == pre) atomicAdd(&h[(bits >> dig_shift) & dmask], 1u);
    __syncthreads();

    unsigned* gh = hist + b * nbins;
    for (int i = tid; i < nbins; i += 256) {
        unsigned v = h[i];
        if (v) atomicAdd(&gh[i], v);
    }
}

// ---------------- Loss: weighted L1, block-reduce, f64 atomic ----------------
__global__ void k_loss(const float* __restrict__ yt, const float* __restrict__ yp,
                       const unsigned* __restrict__ prefix, double* __restrict__ accum) {
    const int tid   = threadIdx.x;
    const int blk   = blockIdx.x;
    const int b     = blk >> 8;
    const int chunk = blk & 255;
    const long base = (long)b * 3 * NPIX;
    const int  o    = (chunk * 256 + tid) * 4;

    float4 p0 = *(const float4*)(yp + base + o);
    float4 p1 = *(const float4*)(yp + base + NPIX + o);
    float4 p2 = *(const float4*)(yp + base + 2 * NPIX + o);
    float4 t0 = *(const float4*)(yt + base + o);
    float4 t1 = *(const float4*)(yt + base + NPIX + o);
    float4 t2 = *(const float4*)(yt + base + 2 * NPIX + o);

    const unsigned thr = prefix[b];
    float s = 0.0f;
    {
        float g = (p0.x + p1.x + p2.x) / 3.0f;
        float w = (__float_as_uint(g) <= thr) ? 0.8f : 0.2f;
        s += w * (fabsf(p0.x - t0.x) + fabsf(p1.x - t1.x) + fabsf(p2.x - t2.x));
    }
    {
        float g = (p0.y + p1.y + p2.y) / 3.0f;
        float w = (__float_as_uint(g) <= thr) ? 0.8f : 0.2f;
        s += w * (fabsf(p0.y - t0.y) + fabsf(p1.y - t1.y) + fabsf(p2.y - t2.y));
    }
    {
        float g = (p0.z + p1.z + p2.z) / 3.0f;
        float w = (__float_as_uint(g) <= thr) ? 0.8f : 0.2f;
        s += w * (fabsf(p0.z - t0.z) + fabsf(p1.z - t1.z) + fabsf(p2.z - t2.z));
    }
    {
        float g = (p0.w + p1.w + p2.w) / 3.0f;
        float w = (__float_as_uint(g) <= thr) ? 0.8f : 0.2f;
        s += w * (fabsf(p0.w - t0.w) + fabsf(p1.w - t1.w) + fabsf(p2.w - t2.w));
    }

    // wave64 shuffle reduce
    for (int off = 32; off > 0; off >>= 1) s += __shfl_down(s, off);
    __shared__ float wsum[4];
    if ((tid & 63) == 0) wsum[tid >> 6] = s;
    __syncthreads();
    if (tid == 0) {
        float tot = wsum[0] + wsum[1] + wsum[2] + wsum[3];
        atomicAdd(accum, (double)tot);
    }
}

__global__ void k_final(const double* __restrict__ accum, float* __restrict__ out) {
    out[0] = (float)(accum[0] / 12582912.0);   // 16*3*512*512
}

extern "C" void kernel_launch(void* const* d_in, const int* in_sizes, int n_in,
                              void* d_out, int out_size, void* d_ws, size_t ws_size,
                              hipStream_t stream) {
    const float* yt = (const float*)d_in[0];   // y_true
    const float* yp = (const float*)d_in[1];   // y_pred
    float* out = (float*)d_out;
    char* ws = (char*)d_ws;

    // ws layout
    unsigned* hist1  = (unsigned*)(ws);              // 16*4096*4 = 262144
    unsigned* hist2  = (unsigned*)(ws + 262144);     // 262144
    unsigned* hist3  = (unsigned*)(ws + 524288);     // 16*256*4 = 16384
    double*   accum  = (double*)(ws + 540672);       // 8
    unsigned* rank   = (unsigned*)(ws + 540736);     // 64
    unsigned* prefix = (unsigned*)(ws + 540800);     // 64

    float* gray = nullptr;
    const size_t gray_off = 1 << 20;
    if (ws_size >= gray_off + (size_t)NB * NPIX * sizeof(float))
        gray = (float*)(ws + gray_off);

    // zero hist1..hist3 + accum (rank/prefix are written before read)
    hipMemsetAsync(ws, 0, 540680, stream);

    k_gray_hist<<<4096, 256, 0, stream>>>(yp, gray, hist1);
    k_scan<<<NB, 256, 0, stream>>>(hist1, NB1, 12, rank, prefix, 1);
    k_refine<<<4096, 256, 0, stream>>>(gray, yp, prefix, hist2, 20, 8, 0xFFFu, NB1);
    k_scan<<<NB, 256, 0, stream>>>(hist2, NB1, 12, rank, prefix, 0);
    k_refine<<<4096, 256, 0, stream>>>(gray, yp, prefix, hist3, 8, 0, 0xFFu, 256);
    k_scan<<<NB, 256, 0, stream>>>(hist3, 256, 8, rank, prefix, 0);
    k_loss<<<4096, 256, 0, stream>>>(yt, yp, prefix, accum);
    k_final<<<1, 1, 0, stream>>>(accum, out);
}

// Round 3
// 158.770 us; speedup vs baseline: 3.6553x; 1.2343x over previous
//
#include <hip/hip_runtime.h>
#include <stdint.h>

#define NB 16
#define NPIX 262144            // 512*512
#define K_RANK 104856u         // int(512*512*0.4 - 1)
#define NB1 4096
#define NACC 64                // accumulator slots, 128B apart (separate cache lines)

// ---------------- Kernel 1: gray + histogram on bits[31:20] ----------------
__global__ void k_gray_hist(const float* __restrict__ yp, float* __restrict__ gray,
                            unsigned* __restrict__ hist1) {
    __shared__ unsigned h[NB1];
    const int tid = threadIdx.x;
    for (int i = tid; i < NB1; i += 256) h[i] = 0;
    __syncthreads();

    const int blk   = blockIdx.x;      // 4096 blocks, 256 per batch
    const int b     = blk >> 8;
    const int chunk = blk & 255;
    const long base = (long)b * 3 * NPIX;
    const int  o    = (chunk * 256 + tid) * 4;

    const float4 c0 = *(const float4*)(yp + base + o);
    const float4 c1 = *(const float4*)(yp + base + NPIX + o);
    const float4 c2 = *(const float4*)(yp + base + 2 * NPIX + o);

    float g0 = (c0.x + c1.x + c2.x) / 3.0f;
    float g1 = (c0.y + c1.y + c2.y) / 3.0f;
    float g2 = (c0.z + c1.z + c2.z) / 3.0f;
    float g3 = (c0.w + c1.w + c2.w) / 3.0f;

    if (gray) {
        *(float4*)(gray + (long)b * NPIX + o) = make_float4(g0, g1, g2, g3);
    }
    atomicAdd(&h[__float_as_uint(g0) >> 20], 1u);
    atomicAdd(&h[__float_as_uint(g1) >> 20], 1u);
    atomicAdd(&h[__float_as_uint(g2) >> 20], 1u);
    atomicAdd(&h[__float_as_uint(g3) >> 20], 1u);
    __syncthreads();

    unsigned* gh = hist1 + b * NB1;
    for (int i = tid; i < NB1; i += 256) {
        unsigned v = h[i];
        if (v) atomicAdd(&gh[i], v);
    }
}

// ---------------- Scan: pick digit containing the rank (parallel) ----------------
__global__ void k_scan(const unsigned* __restrict__ hist, int nbins, int width,
                       unsigned* __restrict__ rank, unsigned* __restrict__ prefix,
                       int first) {
    __shared__ unsigned sh[NB1];
    __shared__ unsigned wave_sums[4];
    const int b   = blockIdx.x;
    const int tid = threadIdx.x;
    const unsigned* hb = hist + b * nbins;

    for (int i = tid; i < nbins; i += 256) sh[i] = hb[i];
    __syncthreads();

    const int per = nbins >> 8;             // 16 (4096 bins) or 1 (256 bins)
    unsigned sum = 0;
    for (int j = 0; j < per; ++j) sum += sh[tid * per + j];

    // inclusive scan within wave64
    unsigned inc = sum;
    for (int off = 1; off < 64; off <<= 1) {
        unsigned v = __shfl_up(inc, off);
        if ((tid & 63) >= off) inc += v;
    }
    if ((tid & 63) == 63) wave_sums[tid >> 6] = inc;
    __syncthreads();
    unsigned wave_off = 0;
    for (int w = 0; w < (tid >> 6); ++w) wave_off += wave_sums[w];
    const unsigned excl = wave_off + inc - sum;   // exclusive prefix of this thread

    const unsigned r = first ? K_RANK : rank[b];
    if (r >= excl && r < excl + sum) {            // exactly one thread
        unsigned cum = excl;
        unsigned d   = (unsigned)(tid * per);
        for (int j = 0; j < per; ++j) {
            unsigned c = sh[tid * per + j];
            if (cum + c > r) { d = (unsigned)(tid * per + j); break; }
            cum += c;
        }
        const unsigned p = first ? 0u : prefix[b];
        rank[b]   = r - cum;
        prefix[b] = (p << width) | d;
    }
}

// ---------------- Refine: histogram next digit among prefix-matching ----------------
__global__ void k_refine(const float* __restrict__ gray, const float* __restrict__ yp,
                         const unsigned* __restrict__ prefix, unsigned* __restrict__ hist,
                         int sel_shift, int dig_shift, unsigned dmask, int nbins) {
    __shared__ unsigned h[NB1];
    const int tid = threadIdx.x;
    for (int i = tid; i < nbins; i += 256) h[i] = 0;
    __syncthreads();

    const int blk   = blockIdx.x;
    const int b     = blk >> 8;
    const int chunk = blk & 255;
    const int o     = (chunk * 256 + tid) * 4;

    float g0, g1, g2, g3;
    if (gray) {
        float4 gv = *(const float4*)(gray + (long)b * NPIX + o);
        g0 = gv.x; g1 = gv.y; g2 = gv.z; g3 = gv.w;
    } else {
        const long base = (long)b * 3 * NPIX;
        float4 c0 = *(const float4*)(yp + base + o);
        float4 c1 = *(const float4*)(yp + base + NPIX + o);
        float4 c2 = *(const float4*)(yp + base + 2 * NPIX + o);
        g0 = (c0.x + c1.x + c2.x) / 3.0f;
        g1 = (c0.y + c1.y + c2.y) / 3.0f;
        g2 = (c0.z + c1.z + c2.z) / 3.0f;
        g3 = (c0.w + c1.w + c2.w) / 3.0f;
    }
    const unsigned pre = prefix[b];
    unsigned bits;
    bits = __float_as_uint(g0);
    if ((bits >> sel_shift) == pre) atomicAdd(&h[(bits >> dig_shift) & dmask], 1u);
    bits = __float_as_uint(g1);
    if ((bits >> sel_shift) == pre) atomicAdd(&h[(bits >> dig_shift) & dmask], 1u);
    bits = __float_as_uint(g2);
    if ((bits >> sel_shift) == pre) atomicAdd(&h[(bits >> dig_shift) & dmask], 1u);
    bits = __float_as_uint(g3);
    if ((bits >> sel_shift) == pre) atomicAdd(&h[(bits >> dig_shift) & dmask], 1u);
    __syncthreads();

    unsigned* gh = hist + b * nbins;
    for (int i = tid; i < nbins; i += 256) {
        unsigned v = h[i];
        if (v) atomicAdd(&gh[i], v);
    }
}

// ---------------- Loss: weighted L1, block-reduce, spread f64 atomics ----------------
__global__ void k_loss(const float* __restrict__ yt, const float* __restrict__ yp,
                       const unsigned* __restrict__ prefix, double* __restrict__ accum) {
    const int tid   = threadIdx.x;
    const int blk   = blockIdx.x;
    const int b     = blk >> 8;
    const int chunk = blk & 255;
    const long base = (long)b * 3 * NPIX;
    const int  o    = (chunk * 256 + tid) * 4;

    float4 p0 = *(const float4*)(yp + base + o);
    float4 p1 = *(const float4*)(yp + base + NPIX + o);
    float4 p2 = *(const float4*)(yp + base + 2 * NPIX + o);
    float4 t0 = *(const float4*)(yt + base + o);
    float4 t1 = *(const float4*)(yt + base + NPIX + o);
    float4 t2 = *(const float4*)(yt + base + 2 * NPIX + o);

    const unsigned thr = prefix[b];
    float s = 0.0f;
    {
        float g = (p0.x + p1.x + p2.x) / 3.0f;
        float w = (__float_as_uint(g) <= thr) ? 0.8f : 0.2f;
        s += w * (fabsf(p0.x - t0.x) + fabsf(p1.x - t1.x) + fabsf(p2.x - t2.x));
    }
    {
        float g = (p0.y + p1.y + p2.y) / 3.0f;
        float w = (__float_as_uint(g) <= thr) ? 0.8f : 0.2f;
        s += w * (fabsf(p0.y - t0.y) + fabsf(p1.y - t1.y) + fabsf(p2.y - t2.y));
    }
    {
        float g = (p0.z + p1.z + p2.z) / 3.0f;
        float w = (__float_as_uint(g) <= thr) ? 0.8f : 0.2f;
        s += w * (fabsf(p0.z - t0.z) + fabsf(p1.z - t1.z) + fabsf(p2.z - t2.z));
    }
    {
        float g = (p0.w + p1.w + p2.w) / 3.0f;
        float w = (__float_as_uint(g) <= thr) ? 0.8f : 0.2f;
        s += w * (fabsf(p0.w - t0.w) + fabsf(p1.w - t1.w) + fabsf(p2.w - t2.w));
    }

    // wave64 shuffle reduce
    for (int off = 32; off > 0; off >>= 1) s += __shfl_down(s, off);
    __shared__ float wsum[4];
    if ((tid & 63) == 0) wsum[tid >> 6] = s;
    __syncthreads();
    if (tid == 0) {
        float tot = wsum[0] + wsum[1] + wsum[2] + wsum[3];
        // spread across 64 cache lines: slot stride = 128B = 16 doubles
        atomicAdd(&accum[(blk & (NACC - 1)) * 16], (double)tot);
    }
}

__global__ void k_final(const double* __restrict__ accum, float* __restrict__ out) {
    double s = 0.0;
    for (int i = 0; i < NACC; ++i) s += accum[i * 16];
    out[0] = (float)(s / 12582912.0);   // 16*3*512*512
}

extern "C" void kernel_launch(void* const* d_in, const int* in_sizes, int n_in,
                              void* d_out, int out_size, void* d_ws, size_t ws_size,
                              hipStream_t stream) {
    const float* yt = (const float*)d_in[0];   // y_true
    const float* yp = (const float*)d_in[1];   // y_pred
    float* out = (float*)d_out;
    char* ws = (char*)d_ws;

    // ws layout
    unsigned* hist1  = (unsigned*)(ws);              // 16*4096*4 = 262144
    unsigned* hist2  = (unsigned*)(ws + 262144);     // 262144
    unsigned* hist3  = (unsigned*)(ws + 524288);     // 16*256*4 = 16384 (ends 540672)
    unsigned* rank   = (unsigned*)(ws + 540672);     // 64
    unsigned* prefix = (unsigned*)(ws + 540736);     // 64
    double*   accum  = (double*)(ws + 544768);       // 64 slots * 128B = 8192 (ends 552960)

    float* gray = nullptr;
    const size_t gray_off = 1 << 20;
    if (ws_size >= gray_off + (size_t)NB * NPIX * sizeof(float))
        gray = (float*)(ws + gray_off);

    // zero hists + accum slots (rank/prefix written before read)
    hipMemsetAsync(ws, 0, 552960, stream);

    k_gray_hist<<<4096, 256, 0, stream>>>(yp, gray, hist1);
    k_scan<<<NB, 256, 0, stream>>>(hist1, NB1, 12, rank, prefix, 1);
    k_refine<<<4096, 256, 0, stream>>>(gray, yp, prefix, hist2, 20, 8, 0xFFFu, NB1);
    k_scan<<<NB, 256, 0, stream>>>(hist2, NB1, 12, rank, prefix, 0);
    k_refine<<<4096, 256, 0, stream>>>(gray, yp, prefix, hist3, 8, 0, 0xFFu, 256);
    k_scan<<<NB, 256, 0, stream>>>(hist3, 256, 8, rank, prefix, 0);
    k_loss<<<4096, 256, 0, stream>>>(yt, yp, prefix, accum);
    k_final<<<1, 1, 0, stream>>>(accum, out);
}